// Round 6
// baseline (441.391 us; speedup 1.0000x reference)
//
#include <hip/hip_runtime.h>
#include <hip/hip_bf16.h>

// Problem constants
constexpr int kB  = 1024;
constexpr int kV  = 6890;
constexpr int kJ  = 24;
constexpr int kNB = 10;
constexpr int kP  = 207;   // 23*9
constexpr int kH  = 17;

constexpr int kN   = kV * 3;      // 20670
constexpr int kKP  = 224;         // K padded: 207 pf + 10 betas + 1 vt + 6 zero
constexpr int kNT  = 1296;        // n-tiles of 16 (N_pad = 20736)
constexpr int kNP  = kNT * 16;    // 20736
constexpr int kVC  = 862;         // v-chunk for k_js part (8 chunks)
constexpr int kTB  = 8;           // batch tile in k_lbs

constexpr int kJsBlocks = kJ * 8;         // 192
constexpr int kPbBlocks = kNP / 64;       // 324
constexpr int kVB2 = (kV + 511) / 512;    // 14 vertex blocks (512 verts each)
constexpr int kJB  = 4;                   // batches per k_jfv block

// Output layout (flat concat, FP32 elements)
constexpr size_t O_VERTS  = 0;
constexpr size_t O_JOINTS = (size_t)kB * kV * 3;              // 21166080
constexpr size_t O_ROT    = O_JOINTS + (size_t)kB * kJ * 3;   // 21239808
constexpr size_t O_JFV    = O_ROT + (size_t)kB * kJ * 9;      // 21460992

// Workspace layout (fp32 element offsets). Total ~11 MB.
constexpr size_t WS_JSP  = 0;                        // 24*8*33 = 6336 floats
constexpr size_t WS_A    = 8192;                     // kB*288  = 294912
constexpr size_t WS_ROOT = WS_A + (size_t)kB * 288;  // kB*3 (padded to 4096)
constexpr size_t WS_ASWZ = WS_ROOT + 4096;           // 1024*224 ushort = 114688 floats
constexpr size_t WS_BSWZ = WS_ASWZ + 114688;         // 1296*7*512 ushort

typedef __attribute__((ext_vector_type(8))) short short8;
typedef __attribute__((ext_vector_type(4))) float float4v;
typedef __attribute__((ext_vector_type(2))) float float2v;

__device__ __forceinline__ unsigned short f2bf(float f) {
    unsigned u = __float_as_uint(f);
    unsigned r = (u + 0x7FFFu + ((u >> 16) & 1u)) >> 16;  // RNE
    return (unsigned short)r;
}

// inline classifier: amb0 is lbs_weights iff its first 24 floats (one weight
// row) sum to ~1.  J_regressor's first 24 entries sum to ~0.003.
__device__ __forceinline__ bool amb0_is_weights(const float* __restrict__ amb0) {
    float s = 0.f;
    #pragma unroll
    for (int i = 0; i < kJ; i++) s += amb0[i];
    return fabsf(s - 1.0f) < 0.5f;
}

// swizzled-A element index for (batch b, k-row k); must match k_gemm's read:
// lane l of tile kt reads shorts [l*8 .. l*8+7] = (quad=l>>4, minr=l&15, kin=0..7)
__device__ __forceinline__ size_t a_idx(int mtile, int minr, int k) {
    int kt = k >> 5, quad = (k >> 3) & 3, kin = k & 7;
    return ((size_t)(mtile * 7 + kt)) * 512 + (size_t)(quad * 128 + minr * 8 + kin);
}

// ---------------------------------------------------------------------------
// k_sfb: fused front-end (independent work, one dispatch).
//   blocks [0, 192):    js partials  partial[(j*8+c)*33 + i] over v-chunk c
//   blocks [192, 516):  swizzled bf16 B (K_pad=224 x N_pad=20736)
// ---------------------------------------------------------------------------
__global__ __launch_bounds__(256) void k_sfb(
    const float* __restrict__ amb0,
    const float* __restrict__ amb1,
    const float* __restrict__ sd,
    const float* __restrict__ vt,
    const float* __restrict__ pd,
    float* __restrict__ partial,
    unsigned short* __restrict__ bswz)
{
    __shared__ unsigned short lds[kKP][68];
    __shared__ float red[4][33];

    int t = threadIdx.x;

    if (blockIdx.x < kJsBlocks) {
        // ----- js part -----
        const float* Jreg = amb0_is_weights(amb0) ? amb1 : amb0;
        int j = blockIdx.x >> 3;
        int c = blockIdx.x & 7;
        int lane = t & 63;
        int wave = t >> 6;

        float acc[33];
        #pragma unroll
        for (int i = 0; i < 33; i++) acc[i] = 0.f;

        int vend = min(kVC * (c + 1), kV);
        for (int v = kVC * c + t; v < vend; v += 256) {
            float w = Jreg[j * kV + v];
            const float* sdp = sd + (size_t)v * 30;
            #pragma unroll
            for (int k = 0; k < 3; k++) {
                #pragma unroll
                for (int l = 0; l < kNB; l++)
                    acc[k * 11 + l] += w * sdp[k * 10 + l];
                acc[k * 11 + 10] += w * vt[v * 3 + k];
            }
        }
        #pragma unroll
        for (int off = 32; off > 0; off >>= 1) {
            #pragma unroll
            for (int i = 0; i < 33; i++)
                acc[i] += __shfl_down(acc[i], off, 64);
        }
        if (lane == 0) {
            #pragma unroll
            for (int i = 0; i < 33; i++) red[wave][i] = acc[i];
        }
        __syncthreads();
        if (t < 33) {
            float s = red[0][t] + red[1][t] + red[2][t] + red[3][t];
            partial[((size_t)j * 8 + c) * 33 + t] = s;
        }
    } else {
        // ----- prep_b part -----
        int g = blockIdx.x - kJsBlocks;
        int n0 = g * 64;

        for (int kbase = 0; kbase < kKP; kbase += 4) {
            int k = kbase + (t >> 6);
            int nl = t & 63;
            int n = n0 + nl;
            float val = 0.f;
            if (n < kN) {
                if (k < kP)                 val = pd[(size_t)k * kN + n];
                else if (k < kP + kNB)      val = sd[(size_t)n * kNB + (k - kP)];
                else if (k == kP + kNB)     val = vt[n];
            }
            lds[k][nl] = f2bf(val);
        }
        __syncthreads();

        #pragma unroll 1
        for (int tt = 0; tt < 4; tt++) {
            int ntile = g * 4 + tt;
            #pragma unroll 1
            for (int kt = 0; kt < 7; kt++) {
                size_t base = ((size_t)ntile * 7 + kt) * 512;
                #pragma unroll
                for (int u = 0; u < 2; u++) {
                    int e = t * 2 + u;
                    int quad = e >> 7, rem = e & 127;
                    int nin = rem >> 3, kin = rem & 7;
                    int k = kt * 32 + quad * 8 + kin;
                    bswz[base + e] = lds[k][tt * 16 + nin];
                }
            }
        }
    }
}

// ---------------------------------------------------------------------------
// k_pose: per-batch rodrigues + FK chain + A matrices.
// ---------------------------------------------------------------------------
__global__ __launch_bounds__(64) void k_pose(
    const float* __restrict__ pose,
    const float* __restrict__ betas,
    const float* __restrict__ gor,
    const float* __restrict__ jsp,
    float* __restrict__ wsA,
    float* __restrict__ wsRoot,
    unsigned short* __restrict__ aswz,
    float* __restrict__ out)
{
    __shared__ float Rsh[kJ][9];
    __shared__ float Jr[kJ][3];
    __shared__ float G[kJ][12];

    int b = blockIdx.x;
    int t = threadIdx.x;
    int mtile = b >> 4, minr = b & 15;

    if (t < kJ) {
        float rx, ry, rz;
        if (t == 0) {
            rx = gor[b * 3 + 0]; ry = gor[b * 3 + 1]; rz = gor[b * 3 + 2];
        } else {
            int o = b * 69 + (t - 1) * 3;
            rx = pose[o]; ry = pose[o + 1]; rz = pose[o + 2];
        }
        float ex = rx + 1e-8f, ey = ry + 1e-8f, ez = rz + 1e-8f;
        float ang = sqrtf(ex * ex + ey * ey + ez * ez);
        float x = rx / ang, y = ry / ang, z = rz / ang;
        float s = sinf(ang), c = cosf(ang), oc = 1.0f - c;
        float r[9];
        r[0] = 1.0f - oc * (y * y + z * z);
        r[1] = -s * z + oc * (x * y);
        r[2] =  s * y + oc * (x * z);
        r[3] =  s * z + oc * (x * y);
        r[4] = 1.0f - oc * (x * x + z * z);
        r[5] = -s * x + oc * (y * z);
        r[6] = -s * y + oc * (x * z);
        r[7] =  s * x + oc * (y * z);
        r[8] = 1.0f - oc * (x * x + y * y);
        #pragma unroll
        for (int i = 0; i < 9; i++) Rsh[t][i] = r[i];
        float* ro = out + O_ROT + (size_t)b * (kJ * 9) + (size_t)t * 9;
        #pragma unroll
        for (int i = 0; i < 9; i++) ro[i] = r[i];
        if (t >= 1) {
            // pose-feature rows 0..206 of swizzled A, bf16
            #pragma unroll
            for (int i = 0; i < 9; i++) {
                int k = (t - 1) * 9 + i;
                float val = r[i] - ((i == 0 || i == 4 || i == 8) ? 1.0f : 0.0f);
                aswz[a_idx(mtile, minr, k)] = f2bf(val);
            }
        }
        // Jr = (reduced js partials) dot [betas | 1]
        float bt[kNB];
        #pragma unroll
        for (int l = 0; l < kNB; l++) bt[l] = betas[b * kNB + l];
        #pragma unroll
        for (int k2 = 0; k2 < 3; k2++) {
            float row[11];
            #pragma unroll
            for (int i = 0; i < 11; i++) row[i] = 0.f;
            #pragma unroll
            for (int c8 = 0; c8 < 8; c8++) {
                const float* pp = jsp + ((size_t)t * 8 + c8) * 33 + k2 * 11;
                #pragma unroll
                for (int i = 0; i < 11; i++) row[i] += pp[i];
            }
            float acc = row[10];
            #pragma unroll
            for (int l = 0; l < kNB; l++) acc += bt[l] * row[l];
            Jr[t][k2] = acc;
        }
    } else if (t < 41 + kJ) {
        // rows 207..223 of swizzled A: betas | 1.0 | zero pad (17 rows)
        int idx = t - kJ;
        if (idx < 17) {
            int k = kP + idx;
            float val = 0.f;
            if (idx < kNB)          val = betas[b * kNB + idx];
            else if (k == kP + kNB) val = 1.0f;
            aswz[a_idx(mtile, minr, k)] = f2bf(val);
        }
    }
    __syncthreads();

    if (t == 0) {
        const int par[kJ] = {-1,0,0,0,1,2,3,4,5,6,7,8,9,9,9,12,13,14,16,17,18,19,20,21};
        #pragma unroll
        for (int m = 0; m < 3; m++) {
            #pragma unroll
            for (int n = 0; n < 3; n++) G[0][m * 4 + n] = Rsh[0][m * 3 + n];
            G[0][m * 4 + 3] = Jr[0][m];
        }
        for (int i = 1; i < kJ; i++) {
            int p = par[i];
            float rel[3];
            #pragma unroll
            for (int k = 0; k < 3; k++) rel[k] = Jr[i][k] - Jr[p][k];
            #pragma unroll
            for (int m = 0; m < 3; m++) {
                float g0 = G[p][m * 4 + 0], g1 = G[p][m * 4 + 1], g2 = G[p][m * 4 + 2];
                #pragma unroll
                for (int n = 0; n < 3; n++) {
                    G[i][m * 4 + n] = g0 * Rsh[i][0 * 3 + n]
                                    + g1 * Rsh[i][1 * 3 + n]
                                    + g2 * Rsh[i][2 * 3 + n];
                }
                G[i][m * 4 + 3] = g0 * rel[0] + g1 * rel[1] + g2 * rel[2]
                                + G[p][m * 4 + 3];
            }
        }
    }
    __syncthreads();

    if (t < kJ) {
        float* Aj = wsA + (size_t)b * 288 + (size_t)t * 12;
        float* jo = out + O_JOINTS + (size_t)b * (kJ * 3) + (size_t)t * 3;
        #pragma unroll
        for (int m = 0; m < 3; m++) {
            float g0 = G[t][m * 4 + 0], g1 = G[t][m * 4 + 1], g2 = G[t][m * 4 + 2];
            Aj[m * 4 + 0] = g0;
            Aj[m * 4 + 1] = g1;
            Aj[m * 4 + 2] = g2;
            Aj[m * 4 + 3] = G[t][m * 4 + 3]
                          - (g0 * Jr[t][0] + g1 * Jr[t][1] + g2 * Jr[t][2]);
            jo[m] = G[t][m * 4 + 3] - G[0][m * 4 + 3];
        }
        if (t == 0) {
            #pragma unroll
            for (int k = 0; k < 3; k++) wsRoot[b * 3 + k] = G[0][k * 4 + 3];
        }
    }
}

// ---------------------------------------------------------------------------
// k_gemm: v_posed[b][n] = A(1024x224) @ B(224x20670) -> out[O_VERTS] (fp32).
// ---------------------------------------------------------------------------
__global__ __launch_bounds__(256) void k_gemm(
    const unsigned short* __restrict__ A,
    const unsigned short* __restrict__ B,
    float* __restrict__ out)
{
    int tid = threadIdx.x;
    int lane = tid & 63;
    int wid = tid >> 6;
    int m0t = blockIdx.y * 8 + (wid >> 1) * 4;
    int n0t = blockIdx.x * 8 + (wid & 1) * 4;

    float4v acc[4][4];
    #pragma unroll
    for (int i = 0; i < 4; i++)
        #pragma unroll
        for (int j = 0; j < 4; j++)
            acc[i][j] = (float4v){0.f, 0.f, 0.f, 0.f};

    #pragma unroll
    for (int kt = 0; kt < 7; kt++) {
        short8 a[4], b[4];
        #pragma unroll
        for (int i = 0; i < 4; i++)
            a[i] = *(const short8*)(A + ((size_t)(m0t + i) * 7 + kt) * 512 + lane * 8);
        #pragma unroll
        for (int j = 0; j < 4; j++)
            b[j] = *(const short8*)(B + ((size_t)(n0t + j) * 7 + kt) * 512 + lane * 8);
        #pragma unroll
        for (int i = 0; i < 4; i++)
            #pragma unroll
            for (int j = 0; j < 4; j++)
                acc[i][j] = __builtin_amdgcn_mfma_f32_16x16x32_bf16(
                    a[i], b[j], acc[i][j], 0, 0, 0);
    }

    int rbase = (lane >> 4) * 4;
    int col = lane & 15;
    #pragma unroll
    for (int i = 0; i < 4; i++) {
        #pragma unroll
        for (int j = 0; j < 4; j++) {
            int n = (n0t + j) * 16 + col;
            if (n < kN) {
                #pragma unroll
                for (int reg = 0; reg < 4; reg++) {
                    int brow = (m0t + i) * 16 + rbase + reg;
                    out[O_VERTS + (size_t)brow * kN + n] = acc[i][j][reg];
                }
            }
        }
    }
}

// ---------------------------------------------------------------------------
// k_lbs: verts only, NV=2 vertex pair per thread.
// r5 counters (80us, VALUBusy 53%, HBM 22%) showed the kernel latency-bound
// on the per-wave A-panel s_load stream (72 dwordx4 per batch-iter).  Total
// s_load traffic scales with waves*batches and is independent of TB -- but
// halves with verts/thread.  Each thread owns the ADJACENT pair (v0, v0+1)
// (kV even -> pairs never straddle the tail), sharing every A-load across
// two T-builds, and the verts RMW becomes 3x float2 (half the VMEM ops).
// Grid 14 x 128 = 1792 blocks; VGPR ~105 -> 4 waves/SIMD at (256,2).
// ---------------------------------------------------------------------------
__global__ __launch_bounds__(256, 2) void k_lbs(
    const float* __restrict__ amb0,
    const float* __restrict__ amb1,
    const float* __restrict__ wsA,
    const float* __restrict__ wsRoot,
    float* __restrict__ out)
{
    const float* W = amb0_is_weights(amb0) ? amb0 : amb1;

    int t = threadIdx.x;
    int v0 = blockIdx.x * 512 + t * 2;
    int b0 = blockIdx.y * kTB;
    bool act = (v0 < kV);                  // kV even: v0,v0+1 all-or-nothing
    int vc = act ? v0 : (kV - 2);

    float wA[kJ], wB[kJ];
    {
        const float4v* Wv4 = (const float4v*)(W + (size_t)vc * kJ);  // 16B-aligned
        #pragma unroll
        for (int q = 0; q < 6; q++) {
            float4v xa = Wv4[q];
            float4v xb = Wv4[q + 6];       // row v0+1 (contiguous)
            wA[q * 4 + 0] = xa[0]; wA[q * 4 + 1] = xa[1];
            wA[q * 4 + 2] = xa[2]; wA[q * 4 + 3] = xa[3];
            wB[q * 4 + 0] = xb[0]; wB[q * 4 + 1] = xb[1];
            wB[q * 4 + 2] = xb[2]; wB[q * 4 + 3] = xb[3];
        }
    }

    #pragma unroll 1
    for (int tb = 0; tb < kTB; tb++) {
        int b = b0 + tb;
        const float4v* A4 = (const float4v*)(wsA + (size_t)b * 288);  // uniform
        float TA[12], TB_[12];
        #pragma unroll
        for (int i = 0; i < 12; i++) { TA[i] = 0.f; TB_[i] = 0.f; }
        #pragma unroll
        for (int j = 0; j < kJ; j++) {
            float wa = wA[j], wb = wB[j];
            float4v a0 = A4[j * 3 + 0];
            float4v a1 = A4[j * 3 + 1];
            float4v a2 = A4[j * 3 + 2];
            #pragma unroll
            for (int q = 0; q < 4; q++) {
                TA[0 + q] += wa * a0[q];
                TA[4 + q] += wa * a1[q];
                TA[8 + q] += wa * a2[q];
                TB_[0 + q] += wb * a0[q];
                TB_[4 + q] += wb * a1[q];
                TB_[8 + q] += wb * a2[q];
            }
        }
        float r0 = wsRoot[(size_t)b * 3 + 0];   // uniform
        float r1 = wsRoot[(size_t)b * 3 + 1];
        float r2 = wsRoot[(size_t)b * 3 + 2];
        if (act) {
            float2v* op = (float2v*)(out + O_VERTS + ((size_t)b * kV + v0) * 3);
            float2v p0 = op[0], p1 = op[1], p2 = op[2];   // 8B-aligned (v0 even)
            float x0 = p0[0], y0 = p0[1], z0 = p1[0];
            float x1 = p1[1], y1 = p2[0], z1 = p2[1];
            float oA0 = TA[0] * x0 + TA[1] * y0 + TA[2]  * z0 + TA[3]  - r0;
            float oA1 = TA[4] * x0 + TA[5] * y0 + TA[6]  * z0 + TA[7]  - r1;
            float oA2 = TA[8] * x0 + TA[9] * y0 + TA[10] * z0 + TA[11] - r2;
            float oB0 = TB_[0] * x1 + TB_[1] * y1 + TB_[2]  * z1 + TB_[3]  - r0;
            float oB1 = TB_[4] * x1 + TB_[5] * y1 + TB_[6]  * z1 + TB_[7]  - r1;
            float oB2 = TB_[8] * x1 + TB_[9] * y1 + TB_[10] * z1 + TB_[11] - r2;
            op[0] = (float2v){oA0, oA1};
            op[1] = (float2v){oA2, oB0};
            op[2] = (float2v){oB1, oB2};
        }
    }
}

// ---------------------------------------------------------------------------
// k_jfv: jfv[b0..b0+3] = Jh @ verts, root17 subtraction folded in.
// 256 blocks x 1024 threads: 4 batches per block, ONE Jh row per wave
// (wave 0 also takes row 16).  Jh L2 traffic drops 4x vs one-batch blocks
// (479 MB -> 120 MB); verts read once from HBM with L1 reuse across waves;
// accumulators only 12-24 VGPR (no r4-style pressure).  16 waves/CU.
// ---------------------------------------------------------------------------
__global__ __launch_bounds__(1024) void k_jfv(
    const float* __restrict__ Jh,
    const float* __restrict__ verts,
    float* __restrict__ out)
{
    int b0 = blockIdx.x * kJB;
    int t = threadIdx.x;
    int wave = t >> 6, lane = t & 63;
    int j0 = wave;                 // rows 0..15
    bool has2 = (wave == 0);       // wave 0 also handles row 16

    float acc0[kJB][3], acc1[kJB][3];
    #pragma unroll
    for (int bb = 0; bb < kJB; bb++)
        #pragma unroll
        for (int k = 0; k < 3; k++) { acc0[bb][k] = 0.f; acc1[bb][k] = 0.f; }

    const float* Jr0 = Jh + (size_t)j0 * kV;
    const float* Jr1 = Jh + (size_t)16 * kV;

    for (int v = lane; v < kV; v += 64) {
        float w0 = Jr0[v];
        float w1 = has2 ? Jr1[v] : 0.f;
        #pragma unroll
        for (int bb = 0; bb < kJB; bb++) {
            const float* vp = verts + ((size_t)(b0 + bb) * kV + v) * 3;
            float vx = vp[0], vy = vp[1], vz = vp[2];
            acc0[bb][0] += w0 * vx; acc0[bb][1] += w0 * vy; acc0[bb][2] += w0 * vz;
            acc1[bb][0] += w1 * vx; acc1[bb][1] += w1 * vy; acc1[bb][2] += w1 * vz;
        }
    }
    #pragma unroll
    for (int off = 32; off > 0; off >>= 1) {
        #pragma unroll
        for (int bb = 0; bb < kJB; bb++)
            #pragma unroll
            for (int k = 0; k < 3; k++) {
                acc0[bb][k] += __shfl_down(acc0[bb][k], off, 64);
                acc1[bb][k] += __shfl_down(acc1[bb][k], off, 64);
            }
    }
    __shared__ float fin[kJB][52];
    if (lane == 0) {
        #pragma unroll
        for (int bb = 0; bb < kJB; bb++)
            #pragma unroll
            for (int k = 0; k < 3; k++) {
                fin[bb][j0 * 3 + k] = acc0[bb][k];
                if (has2) fin[bb][48 + k] = acc1[bb][k];
            }
    }
    __syncthreads();
    if (t < kJB * 51) {
        int bb = t / 51, i = t - bb * 51;
        // verts already root-subtracted; subtracting the per-axis j'=0 sums
        // reproduces jfv - root17 exactly (Jh rows sum to 1)
        out[O_JFV + (size_t)(b0 + bb) * 51 + i] = fin[bb][i] - fin[bb][i % 3];
    }
}

extern "C" void kernel_launch(void* const* d_in, const int* in_sizes, int n_in,
                              void* d_out, int out_size, void* d_ws, size_t ws_size,
                              hipStream_t stream) {
    const float *pose = nullptr, *betas = nullptr, *gor = nullptr, *vt = nullptr,
                *sd = nullptr, *pd = nullptr, *Jh = nullptr;
    const float *amb0 = nullptr, *amb1 = nullptr;
    for (int i = 0; i < n_in; i++) {
        const float* p = (const float*)d_in[i];
        switch (in_sizes[i]) {
            case 70656:   pose  = p; break;
            case 10240:   betas = p; break;
            case 3072:    gor   = p; break;
            case 20670:   vt    = p; break;
            case 206700:  sd    = p; break;
            case 4278690: pd    = p; break;
            case 117130:  Jh    = p; break;
            case 165360:  if (!amb0) amb0 = p; else amb1 = p; break;
            default: break;
        }
    }

    float* ws = (float*)d_ws;
    float* jsp     = ws + WS_JSP;
    float* wsA     = ws + WS_A;
    float* wsRoot  = ws + WS_ROOT;
    unsigned short* aswz = (unsigned short*)(ws + WS_ASWZ);
    unsigned short* bswz = (unsigned short*)(ws + WS_BSWZ);

    float* out = (float*)d_out;

    k_sfb  <<<dim3(kJsBlocks + kPbBlocks), dim3(256), 0, stream>>>(
        amb0, amb1, sd, vt, pd, jsp, bswz);
    k_pose <<<dim3(kB),                 dim3(64),  0, stream>>>(
        pose, betas, gor, jsp, wsA, wsRoot, aswz, out);
    k_gemm <<<dim3(kNT / 8, kB / 128),  dim3(256), 0, stream>>>(aswz, bswz, out);
    k_lbs  <<<dim3(kVB2, kB / kTB),     dim3(256), 0, stream>>>(
        amb0, amb1, wsA, wsRoot, out);
    k_jfv  <<<dim3(kB / kJB),           dim3(1024), 0, stream>>>(
        Jh, out + O_VERTS, out);
}

// Round 7
// 312.563 us; speedup vs baseline: 1.4122x; 1.4122x over previous
//
#include <hip/hip_runtime.h>
#include <hip/hip_bf16.h>

// Problem constants
constexpr int kB  = 1024;
constexpr int kV  = 6890;
constexpr int kJ  = 24;
constexpr int kNB = 10;
constexpr int kP  = 207;   // 23*9
constexpr int kH  = 17;

constexpr int kN   = kV * 3;      // 20670
constexpr int kKP  = 224;         // K padded: 207 pf + 10 betas + 1 vt + 6 zero
constexpr int kNT  = 1296;        // n-tiles of 16 (N_pad = 20736)
constexpr int kNP  = kNT * 16;    // 20736
constexpr int kVC  = 862;         // v-chunk for k_js part (8 chunks)
constexpr int kTB  = 4;           // batch tile in k_lbs (r5 proved 8; 4 doubles blocks at same VGPR)

constexpr int kJsBlocks = kJ * 8;         // 192
constexpr int kPbBlocks = kNP / 64;       // 324
constexpr int kVB = (kV + 255) / 256;     // 27 vertex blocks
constexpr int kJB  = 4;                   // batches per k_jfv block

// Output layout (flat concat, FP32 elements)
constexpr size_t O_VERTS  = 0;
constexpr size_t O_JOINTS = (size_t)kB * kV * 3;              // 21166080
constexpr size_t O_ROT    = O_JOINTS + (size_t)kB * kJ * 3;   // 21239808
constexpr size_t O_JFV    = O_ROT + (size_t)kB * kJ * 9;      // 21460992

// Workspace layout (fp32 element offsets). Total ~11 MB.
constexpr size_t WS_JSP  = 0;                        // 24*8*33 = 6336 floats
constexpr size_t WS_A    = 8192;                     // kB*288  = 294912
constexpr size_t WS_ROOT = WS_A + (size_t)kB * 288;  // kB*3 (padded to 4096)
constexpr size_t WS_ASWZ = WS_ROOT + 4096;           // 1024*224 ushort = 114688 floats
constexpr size_t WS_BSWZ = WS_ASWZ + 114688;         // 1296*7*512 ushort

typedef __attribute__((ext_vector_type(8))) short short8;
typedef __attribute__((ext_vector_type(4))) float float4v;

__device__ __forceinline__ unsigned short f2bf(float f) {
    unsigned u = __float_as_uint(f);
    unsigned r = (u + 0x7FFFu + ((u >> 16) & 1u)) >> 16;  // RNE
    return (unsigned short)r;
}

// inline classifier: amb0 is lbs_weights iff its first 24 floats (one weight
// row) sum to ~1.  J_regressor's first 24 entries sum to ~0.003.
__device__ __forceinline__ bool amb0_is_weights(const float* __restrict__ amb0) {
    float s = 0.f;
    #pragma unroll
    for (int i = 0; i < kJ; i++) s += amb0[i];
    return fabsf(s - 1.0f) < 0.5f;
}

// swizzled-A element index for (batch b, k-row k); must match k_gemm's read:
// lane l of tile kt reads shorts [l*8 .. l*8+7] = (quad=l>>4, minr=l&15, kin=0..7)
__device__ __forceinline__ size_t a_idx(int mtile, int minr, int k) {
    int kt = k >> 5, quad = (k >> 3) & 3, kin = k & 7;
    return ((size_t)(mtile * 7 + kt)) * 512 + (size_t)(quad * 128 + minr * 8 + kin);
}

// ---------------------------------------------------------------------------
// k_sfb: fused front-end (independent work, one dispatch).
//   blocks [0, 192):    js partials  partial[(j*8+c)*33 + i] over v-chunk c
//   blocks [192, 516):  swizzled bf16 B (K_pad=224 x N_pad=20736)
// ---------------------------------------------------------------------------
__global__ __launch_bounds__(256) void k_sfb(
    const float* __restrict__ amb0,
    const float* __restrict__ amb1,
    const float* __restrict__ sd,
    const float* __restrict__ vt,
    const float* __restrict__ pd,
    float* __restrict__ partial,
    unsigned short* __restrict__ bswz)
{
    __shared__ unsigned short lds[kKP][68];
    __shared__ float red[4][33];

    int t = threadIdx.x;

    if (blockIdx.x < kJsBlocks) {
        // ----- js part -----
        const float* Jreg = amb0_is_weights(amb0) ? amb1 : amb0;
        int j = blockIdx.x >> 3;
        int c = blockIdx.x & 7;
        int lane = t & 63;
        int wave = t >> 6;

        float acc[33];
        #pragma unroll
        for (int i = 0; i < 33; i++) acc[i] = 0.f;

        int vend = min(kVC * (c + 1), kV);
        for (int v = kVC * c + t; v < vend; v += 256) {
            float w = Jreg[j * kV + v];
            const float* sdp = sd + (size_t)v * 30;
            #pragma unroll
            for (int k = 0; k < 3; k++) {
                #pragma unroll
                for (int l = 0; l < kNB; l++)
                    acc[k * 11 + l] += w * sdp[k * 10 + l];
                acc[k * 11 + 10] += w * vt[v * 3 + k];
            }
        }
        #pragma unroll
        for (int off = 32; off > 0; off >>= 1) {
            #pragma unroll
            for (int i = 0; i < 33; i++)
                acc[i] += __shfl_down(acc[i], off, 64);
        }
        if (lane == 0) {
            #pragma unroll
            for (int i = 0; i < 33; i++) red[wave][i] = acc[i];
        }
        __syncthreads();
        if (t < 33) {
            float s = red[0][t] + red[1][t] + red[2][t] + red[3][t];
            partial[((size_t)j * 8 + c) * 33 + t] = s;
        }
    } else {
        // ----- prep_b part -----
        int g = blockIdx.x - kJsBlocks;
        int n0 = g * 64;

        for (int kbase = 0; kbase < kKP; kbase += 4) {
            int k = kbase + (t >> 6);
            int nl = t & 63;
            int n = n0 + nl;
            float val = 0.f;
            if (n < kN) {
                if (k < kP)                 val = pd[(size_t)k * kN + n];
                else if (k < kP + kNB)      val = sd[(size_t)n * kNB + (k - kP)];
                else if (k == kP + kNB)     val = vt[n];
            }
            lds[k][nl] = f2bf(val);
        }
        __syncthreads();

        #pragma unroll 1
        for (int tt = 0; tt < 4; tt++) {
            int ntile = g * 4 + tt;
            #pragma unroll 1
            for (int kt = 0; kt < 7; kt++) {
                size_t base = ((size_t)ntile * 7 + kt) * 512;
                #pragma unroll
                for (int u = 0; u < 2; u++) {
                    int e = t * 2 + u;
                    int quad = e >> 7, rem = e & 127;
                    int nin = rem >> 3, kin = rem & 7;
                    int k = kt * 32 + quad * 8 + kin;
                    bswz[base + e] = lds[k][tt * 16 + nin];
                }
            }
        }
    }
}

// ---------------------------------------------------------------------------
// k_pose: per-batch rodrigues + FK chain + A matrices.
// ---------------------------------------------------------------------------
__global__ __launch_bounds__(64) void k_pose(
    const float* __restrict__ pose,
    const float* __restrict__ betas,
    const float* __restrict__ gor,
    const float* __restrict__ jsp,
    float* __restrict__ wsA,
    float* __restrict__ wsRoot,
    unsigned short* __restrict__ aswz,
    float* __restrict__ out)
{
    __shared__ float Rsh[kJ][9];
    __shared__ float Jr[kJ][3];
    __shared__ float G[kJ][12];

    int b = blockIdx.x;
    int t = threadIdx.x;
    int mtile = b >> 4, minr = b & 15;

    if (t < kJ) {
        float rx, ry, rz;
        if (t == 0) {
            rx = gor[b * 3 + 0]; ry = gor[b * 3 + 1]; rz = gor[b * 3 + 2];
        } else {
            int o = b * 69 + (t - 1) * 3;
            rx = pose[o]; ry = pose[o + 1]; rz = pose[o + 2];
        }
        float ex = rx + 1e-8f, ey = ry + 1e-8f, ez = rz + 1e-8f;
        float ang = sqrtf(ex * ex + ey * ey + ez * ez);
        float x = rx / ang, y = ry / ang, z = rz / ang;
        float s = sinf(ang), c = cosf(ang), oc = 1.0f - c;
        float r[9];
        r[0] = 1.0f - oc * (y * y + z * z);
        r[1] = -s * z + oc * (x * y);
        r[2] =  s * y + oc * (x * z);
        r[3] =  s * z + oc * (x * y);
        r[4] = 1.0f - oc * (x * x + z * z);
        r[5] = -s * x + oc * (y * z);
        r[6] = -s * y + oc * (x * z);
        r[7] =  s * x + oc * (y * z);
        r[8] = 1.0f - oc * (x * x + y * y);
        #pragma unroll
        for (int i = 0; i < 9; i++) Rsh[t][i] = r[i];
        float* ro = out + O_ROT + (size_t)b * (kJ * 9) + (size_t)t * 9;
        #pragma unroll
        for (int i = 0; i < 9; i++) ro[i] = r[i];
        if (t >= 1) {
            // pose-feature rows 0..206 of swizzled A, bf16
            #pragma unroll
            for (int i = 0; i < 9; i++) {
                int k = (t - 1) * 9 + i;
                float val = r[i] - ((i == 0 || i == 4 || i == 8) ? 1.0f : 0.0f);
                aswz[a_idx(mtile, minr, k)] = f2bf(val);
            }
        }
        // Jr = (reduced js partials) dot [betas | 1]
        float bt[kNB];
        #pragma unroll
        for (int l = 0; l < kNB; l++) bt[l] = betas[b * kNB + l];
        #pragma unroll
        for (int k2 = 0; k2 < 3; k2++) {
            float row[11];
            #pragma unroll
            for (int i = 0; i < 11; i++) row[i] = 0.f;
            #pragma unroll
            for (int c8 = 0; c8 < 8; c8++) {
                const float* pp = jsp + ((size_t)t * 8 + c8) * 33 + k2 * 11;
                #pragma unroll
                for (int i = 0; i < 11; i++) row[i] += pp[i];
            }
            float acc = row[10];
            #pragma unroll
            for (int l = 0; l < kNB; l++) acc += bt[l] * row[l];
            Jr[t][k2] = acc;
        }
    } else if (t < 41 + kJ) {
        // rows 207..223 of swizzled A: betas | 1.0 | zero pad (17 rows)
        int idx = t - kJ;
        if (idx < 17) {
            int k = kP + idx;
            float val = 0.f;
            if (idx < kNB)          val = betas[b * kNB + idx];
            else if (k == kP + kNB) val = 1.0f;
            aswz[a_idx(mtile, minr, k)] = f2bf(val);
        }
    }
    __syncthreads();

    if (t == 0) {
        const int par[kJ] = {-1,0,0,0,1,2,3,4,5,6,7,8,9,9,9,12,13,14,16,17,18,19,20,21};
        #pragma unroll
        for (int m = 0; m < 3; m++) {
            #pragma unroll
            for (int n = 0; n < 3; n++) G[0][m * 4 + n] = Rsh[0][m * 3 + n];
            G[0][m * 4 + 3] = Jr[0][m];
        }
        for (int i = 1; i < kJ; i++) {
            int p = par[i];
            float rel[3];
            #pragma unroll
            for (int k = 0; k < 3; k++) rel[k] = Jr[i][k] - Jr[p][k];
            #pragma unroll
            for (int m = 0; m < 3; m++) {
                float g0 = G[p][m * 4 + 0], g1 = G[p][m * 4 + 1], g2 = G[p][m * 4 + 2];
                #pragma unroll
                for (int n = 0; n < 3; n++) {
                    G[i][m * 4 + n] = g0 * Rsh[i][0 * 3 + n]
                                    + g1 * Rsh[i][1 * 3 + n]
                                    + g2 * Rsh[i][2 * 3 + n];
                }
                G[i][m * 4 + 3] = g0 * rel[0] + g1 * rel[1] + g2 * rel[2]
                                + G[p][m * 4 + 3];
            }
        }
    }
    __syncthreads();

    if (t < kJ) {
        float* Aj = wsA + (size_t)b * 288 + (size_t)t * 12;
        float* jo = out + O_JOINTS + (size_t)b * (kJ * 3) + (size_t)t * 3;
        #pragma unroll
        for (int m = 0; m < 3; m++) {
            float g0 = G[t][m * 4 + 0], g1 = G[t][m * 4 + 1], g2 = G[t][m * 4 + 2];
            Aj[m * 4 + 0] = g0;
            Aj[m * 4 + 1] = g1;
            Aj[m * 4 + 2] = g2;
            Aj[m * 4 + 3] = G[t][m * 4 + 3]
                          - (g0 * Jr[t][0] + g1 * Jr[t][1] + g2 * Jr[t][2]);
            jo[m] = G[t][m * 4 + 3] - G[0][m * 4 + 3];
        }
        if (t == 0) {
            #pragma unroll
            for (int k = 0; k < 3; k++) wsRoot[b * 3 + k] = G[0][k * 4 + 3];
        }
    }
}

// ---------------------------------------------------------------------------
// k_gemm: v_posed[b][n] = A(1024x224) @ B(224x20670) -> out[O_VERTS] (fp32).
// ---------------------------------------------------------------------------
__global__ __launch_bounds__(256) void k_gemm(
    const unsigned short* __restrict__ A,
    const unsigned short* __restrict__ B,
    float* __restrict__ out)
{
    int tid = threadIdx.x;
    int lane = tid & 63;
    int wid = tid >> 6;
    int m0t = blockIdx.y * 8 + (wid >> 1) * 4;
    int n0t = blockIdx.x * 8 + (wid & 1) * 4;

    float4v acc[4][4];
    #pragma unroll
    for (int i = 0; i < 4; i++)
        #pragma unroll
        for (int j = 0; j < 4; j++)
            acc[i][j] = (float4v){0.f, 0.f, 0.f, 0.f};

    #pragma unroll
    for (int kt = 0; kt < 7; kt++) {
        short8 a[4], b[4];
        #pragma unroll
        for (int i = 0; i < 4; i++)
            a[i] = *(const short8*)(A + ((size_t)(m0t + i) * 7 + kt) * 512 + lane * 8);
        #pragma unroll
        for (int j = 0; j < 4; j++)
            b[j] = *(const short8*)(B + ((size_t)(n0t + j) * 7 + kt) * 512 + lane * 8);
        #pragma unroll
        for (int i = 0; i < 4; i++)
            #pragma unroll
            for (int j = 0; j < 4; j++)
                acc[i][j] = __builtin_amdgcn_mfma_f32_16x16x32_bf16(
                    a[i], b[j], acc[i][j], 0, 0, 0);
    }

    int rbase = (lane >> 4) * 4;
    int col = lane & 15;
    #pragma unroll
    for (int i = 0; i < 4; i++) {
        #pragma unroll
        for (int j = 0; j < 4; j++) {
            int n = (n0t + j) * 16 + col;
            if (n < kN) {
                #pragma unroll
                for (int reg = 0; reg < 4; reg++) {
                    int brow = (m0t + i) * 16 + rbase + reg;
                    out[O_VERTS + (size_t)brow * kN + n] = acc[i][j][reg];
                }
            }
        }
    }
}

// ---------------------------------------------------------------------------
// k_lbs: verts only -- EXACT r5 body (80us, VGPR 48, zero scratch), with
// TB 8->4: grid 27 x 256 = 6912 blocks (2x r5 parallelism).  Total s_load
// traffic is invariant (waves x batches constant); only the small W reload
// doubles.  r6's NV=2 lesson: resident-wave count dominates per-wave
// cleverness; never raise VGPR here.
// ---------------------------------------------------------------------------
__global__ __launch_bounds__(256, 4) void k_lbs(
    const float* __restrict__ amb0,
    const float* __restrict__ amb1,
    const float* __restrict__ wsA,
    const float* __restrict__ wsRoot,
    float* __restrict__ out)
{
    const float* W = amb0_is_weights(amb0) ? amb0 : amb1;

    int t = threadIdx.x;
    int v = blockIdx.x * 256 + t;
    int b0 = blockIdx.y * kTB;
    bool active = (v < kV);
    int vc = active ? v : (kV - 1);

    float w[kJ];
    {
        const float4v* Wv4 = (const float4v*)(W + (size_t)vc * kJ);  // 16B-aligned
        #pragma unroll
        for (int q = 0; q < 6; q++) {
            float4v x = Wv4[q];
            w[q * 4 + 0] = x[0]; w[q * 4 + 1] = x[1];
            w[q * 4 + 2] = x[2]; w[q * 4 + 3] = x[3];
        }
    }

    #pragma unroll 1
    for (int tb = 0; tb < kTB; tb++) {
        int b = b0 + tb;
        const float4v* A4 = (const float4v*)(wsA + (size_t)b * 288);  // uniform
        float T0[4] = {0.f, 0.f, 0.f, 0.f};
        float T1[4] = {0.f, 0.f, 0.f, 0.f};
        float T2[4] = {0.f, 0.f, 0.f, 0.f};
        #pragma unroll
        for (int j = 0; j < kJ; j++) {
            float wj = w[j];
            float4v a0 = A4[j * 3 + 0];
            float4v a1 = A4[j * 3 + 1];
            float4v a2 = A4[j * 3 + 2];
            #pragma unroll
            for (int q = 0; q < 4; q++) {
                T0[q] += wj * a0[q];
                T1[q] += wj * a1[q];
                T2[q] += wj * a2[q];
            }
        }
        float r0 = wsRoot[(size_t)b * 3 + 0];   // uniform
        float r1 = wsRoot[(size_t)b * 3 + 1];
        float r2 = wsRoot[(size_t)b * 3 + 2];
        if (active) {
            float* op = out + O_VERTS + ((size_t)b * kV + v) * 3;
            float x = op[0], y = op[1], z = op[2];
            op[0] = T0[0] * x + T0[1] * y + T0[2] * z + T0[3] - r0;
            op[1] = T1[0] * x + T1[1] * y + T1[2] * z + T1[3] - r1;
            op[2] = T2[0] * x + T2[1] * y + T2[2] * z + T2[3] - r2;
        }
    }
}

// ---------------------------------------------------------------------------
// k_jfv: jfv[b0..b0+3] = Jh @ verts, root17 subtraction folded in.
// 256 blocks x 1024 threads: 4 batches per block, ONE Jh row per wave
// (wave 0 also takes row 16).  Jh L2 traffic 4x lower than one-batch blocks;
// verts read once from HBM with L1 reuse across waves.  (r6-verified.)
// ---------------------------------------------------------------------------
__global__ __launch_bounds__(1024) void k_jfv(
    const float* __restrict__ Jh,
    const float* __restrict__ verts,
    float* __restrict__ out)
{
    int b0 = blockIdx.x * kJB;
    int t = threadIdx.x;
    int wave = t >> 6, lane = t & 63;
    int j0 = wave;                 // rows 0..15
    bool has2 = (wave == 0);       // wave 0 also handles row 16

    float acc0[kJB][3], acc1[kJB][3];
    #pragma unroll
    for (int bb = 0; bb < kJB; bb++)
        #pragma unroll
        for (int k = 0; k < 3; k++) { acc0[bb][k] = 0.f; acc1[bb][k] = 0.f; }

    const float* Jr0 = Jh + (size_t)j0 * kV;
    const float* Jr1 = Jh + (size_t)16 * kV;

    for (int v = lane; v < kV; v += 64) {
        float w0 = Jr0[v];
        float w1 = has2 ? Jr1[v] : 0.f;
        #pragma unroll
        for (int bb = 0; bb < kJB; bb++) {
            const float* vp = verts + ((size_t)(b0 + bb) * kV + v) * 3;
            float vx = vp[0], vy = vp[1], vz = vp[2];
            acc0[bb][0] += w0 * vx; acc0[bb][1] += w0 * vy; acc0[bb][2] += w0 * vz;
            acc1[bb][0] += w1 * vx; acc1[bb][1] += w1 * vy; acc1[bb][2] += w1 * vz;
        }
    }
    #pragma unroll
    for (int off = 32; off > 0; off >>= 1) {
        #pragma unroll
        for (int bb = 0; bb < kJB; bb++)
            #pragma unroll
            for (int k = 0; k < 3; k++) {
                acc0[bb][k] += __shfl_down(acc0[bb][k], off, 64);
                acc1[bb][k] += __shfl_down(acc1[bb][k], off, 64);
            }
    }
    __shared__ float fin[kJB][52];
    if (lane == 0) {
        #pragma unroll
        for (int bb = 0; bb < kJB; bb++)
            #pragma unroll
            for (int k = 0; k < 3; k++) {
                fin[bb][j0 * 3 + k] = acc0[bb][k];
                if (has2) fin[bb][48 + k] = acc1[bb][k];
            }
    }
    __syncthreads();
    if (t < kJB * 51) {
        int bb = t / 51, i = t - bb * 51;
        // verts already root-subtracted; subtracting the per-axis j'=0 sums
        // reproduces jfv - root17 exactly (Jh rows sum to 1)
        out[O_JFV + (size_t)(b0 + bb) * 51 + i] = fin[bb][i] - fin[bb][i % 3];
    }
}

extern "C" void kernel_launch(void* const* d_in, const int* in_sizes, int n_in,
                              void* d_out, int out_size, void* d_ws, size_t ws_size,
                              hipStream_t stream) {
    const float *pose = nullptr, *betas = nullptr, *gor = nullptr, *vt = nullptr,
                *sd = nullptr, *pd = nullptr, *Jh = nullptr;
    const float *amb0 = nullptr, *amb1 = nullptr;
    for (int i = 0; i < n_in; i++) {
        const float* p = (const float*)d_in[i];
        switch (in_sizes[i]) {
            case 70656:   pose  = p; break;
            case 10240:   betas = p; break;
            case 3072:    gor   = p; break;
            case 20670:   vt    = p; break;
            case 206700:  sd    = p; break;
            case 4278690: pd    = p; break;
            case 117130:  Jh    = p; break;
            case 165360:  if (!amb0) amb0 = p; else amb1 = p; break;
            default: break;
        }
    }

    float* ws = (float*)d_ws;
    float* jsp     = ws + WS_JSP;
    float* wsA     = ws + WS_A;
    float* wsRoot  = ws + WS_ROOT;
    unsigned short* aswz = (unsigned short*)(ws + WS_ASWZ);
    unsigned short* bswz = (unsigned short*)(ws + WS_BSWZ);

    float* out = (float*)d_out;

    k_sfb  <<<dim3(kJsBlocks + kPbBlocks), dim3(256), 0, stream>>>(
        amb0, amb1, sd, vt, pd, jsp, bswz);
    k_pose <<<dim3(kB),                 dim3(64),  0, stream>>>(
        pose, betas, gor, jsp, wsA, wsRoot, aswz, out);
    k_gemm <<<dim3(kNT / 8, kB / 128),  dim3(256), 0, stream>>>(aswz, bswz, out);
    k_lbs  <<<dim3(kVB, kB / kTB),      dim3(256), 0, stream>>>(
        amb0, amb1, wsA, wsRoot, out);
    k_jfv  <<<dim3(kB / kJB),           dim3(1024), 0, stream>>>(
        Jh, out + O_VERTS, out);
}

// Round 9
// 283.749 us; speedup vs baseline: 1.5556x; 1.1015x over previous
//
#include <hip/hip_runtime.h>
#include <hip/hip_bf16.h>

// Problem constants
constexpr int kB  = 1024;
constexpr int kV  = 6890;
constexpr int kJ  = 24;
constexpr int kNB = 10;
constexpr int kP  = 207;   // 23*9
constexpr int kH  = 17;

constexpr int kN   = kV * 3;      // 20670
constexpr int kKP  = 224;         // K padded: 207 pf + 10 betas + 1 vt + 6 zero
constexpr int kNT  = 1296;        // n-tiles of 16 (N_pad = 20736)
constexpr int kNP  = kNT * 16;    // 20736
constexpr int kVC  = 862;         // v-chunk for k_js part (8 chunks)

constexpr int kJsBlocks = kJ * 8;         // 192
constexpr int kPbBlocks = kNP / 64;       // 324
constexpr int kJB  = 4;                   // batches per k_jfv block
constexpr int kLbsTB = 8;                 // batches per k_lbs block

// Output layout (flat concat, FP32 elements)
constexpr size_t O_VERTS  = 0;
constexpr size_t O_JOINTS = (size_t)kB * kV * 3;              // 21166080
constexpr size_t O_ROT    = O_JOINTS + (size_t)kB * kJ * 3;   // 21239808
constexpr size_t O_JFV    = O_ROT + (size_t)kB * kJ * 9;      // 21460992

// Workspace layout (fp32 element offsets).  End = 2,977,792 floats = 11.91 MB
// (within the 12.0 MB envelope proven by the original session).  r8 FAILED on
// an overlap: WS_WHI was offset by half of bswz's true float size.  bswz =
// 1296*7*512 ushorts = 2,322,432 FLOATS.  All offsets re-derived and checked.
constexpr size_t WS_JSP  = 0;                         // 6336 floats
constexpr size_t WS_ROOT = 8192;                      // kB*3 (pad)
constexpr size_t WS_ABHI = 16384;                     // 1024*512 ushort = 262144 floats
constexpr size_t WS_ABLO = WS_ABHI + 262144;          // 278528
constexpr size_t WS_ASWZ = WS_ABLO + 262144;          // 540672: 1024*224 ushort = 114688 floats
constexpr size_t WS_BSWZ = WS_ASWZ + 114688;          // 655360: 2322432 floats

typedef __attribute__((ext_vector_type(8))) short short8;
typedef __attribute__((ext_vector_type(4))) float float4v;

__device__ __forceinline__ unsigned short f2bf(float f) {
    unsigned u = __float_as_uint(f);
    unsigned r = (u + 0x7FFFu + ((u >> 16) & 1u)) >> 16;  // RNE
    return (unsigned short)r;
}
__device__ __forceinline__ float bf2f(unsigned short h) {
    return __uint_as_float((unsigned)h << 16);
}

// inline classifier: amb0 is lbs_weights iff its first 24 floats sum to ~1.
__device__ __forceinline__ bool amb0_is_weights(const float* __restrict__ amb0) {
    float s = 0.f;
    #pragma unroll
    for (int i = 0; i < kJ; i++) s += amb0[i];
    return fabsf(s - 1.0f) < 0.5f;
}

// swizzled-A element index for (batch b, k-row k); matches k_gemm's read.
__device__ __forceinline__ size_t a_idx(int mtile, int minr, int k) {
    int kt = k >> 5, quad = (k >> 3) & 3, kin = k & 7;
    return ((size_t)(mtile * 7 + kt)) * 512 + (size_t)(quad * 128 + minr * 8 + kin);
}

// ---------------------------------------------------------------------------
// k_sfb: fused front-end (r7-verified body: js + prep_b only).
// ---------------------------------------------------------------------------
__global__ __launch_bounds__(256) void k_sfb(
    const float* __restrict__ amb0,
    const float* __restrict__ amb1,
    const float* __restrict__ sd,
    const float* __restrict__ vt,
    const float* __restrict__ pd,
    float* __restrict__ partial,
    unsigned short* __restrict__ bswz)
{
    __shared__ unsigned short lds[kKP][68];
    __shared__ float red[4][33];

    int t = threadIdx.x;

    if (blockIdx.x < kJsBlocks) {
        // ----- js part -----
        const float* Jreg = amb0_is_weights(amb0) ? amb1 : amb0;
        int j = blockIdx.x >> 3;
        int c = blockIdx.x & 7;
        int lane = t & 63;
        int wave = t >> 6;

        float acc[33];
        #pragma unroll
        for (int i = 0; i < 33; i++) acc[i] = 0.f;

        int vend = min(kVC * (c + 1), kV);
        for (int v = kVC * c + t; v < vend; v += 256) {
            float w = Jreg[j * kV + v];
            const float* sdp = sd + (size_t)v * 30;
            #pragma unroll
            for (int k = 0; k < 3; k++) {
                #pragma unroll
                for (int l = 0; l < kNB; l++)
                    acc[k * 11 + l] += w * sdp[k * 10 + l];
                acc[k * 11 + 10] += w * vt[v * 3 + k];
            }
        }
        #pragma unroll
        for (int off = 32; off > 0; off >>= 1) {
            #pragma unroll
            for (int i = 0; i < 33; i++)
                acc[i] += __shfl_down(acc[i], off, 64);
        }
        if (lane == 0) {
            #pragma unroll
            for (int i = 0; i < 33; i++) red[wave][i] = acc[i];
        }
        __syncthreads();
        if (t < 33) {
            float s = red[0][t] + red[1][t] + red[2][t] + red[3][t];
            partial[((size_t)j * 8 + c) * 33 + t] = s;
        }
    } else {
        // ----- prep_b part -----
        int g = blockIdx.x - kJsBlocks;
        int n0 = g * 64;

        for (int kbase = 0; kbase < kKP; kbase += 4) {
            int k = kbase + (t >> 6);
            int nl = t & 63;
            int n = n0 + nl;
            float val = 0.f;
            if (n < kN) {
                if (k < kP)                 val = pd[(size_t)k * kN + n];
                else if (k < kP + kNB)      val = sd[(size_t)n * kNB + (k - kP)];
                else if (k == kP + kNB)     val = vt[n];
            }
            lds[k][nl] = f2bf(val);
        }
        __syncthreads();

        #pragma unroll 1
        for (int tt = 0; tt < 4; tt++) {
            int ntile = g * 4 + tt;
            #pragma unroll 1
            for (int kt = 0; kt < 7; kt++) {
                size_t base = ((size_t)ntile * 7 + kt) * 512;
                #pragma unroll
                for (int u = 0; u < 2; u++) {
                    int e = t * 2 + u;
                    int quad = e >> 7, rem = e & 127;
                    int nin = rem >> 3, kin = rem & 7;
                    int k = kt * 32 + quad * 8 + kin;
                    bswz[base + e] = lds[k][tt * 16 + nin];
                }
            }
        }
    }
}

// ---------------------------------------------------------------------------
// k_pose: per-batch rodrigues + FK chain + A matrices.
// Emits the per-batch bf16 hi/lo A_flat fragment (MFMA B-operand:
// lane l holds A_flat[j=(l>>4)*8+e][m=l&15]).  wsA buffer dropped.
// ---------------------------------------------------------------------------
__global__ __launch_bounds__(64) void k_pose(
    const float* __restrict__ pose,
    const float* __restrict__ betas,
    const float* __restrict__ gor,
    const float* __restrict__ jsp,
    float* __restrict__ wsRoot,
    unsigned short* __restrict__ aswz,
    unsigned short* __restrict__ abhi,
    unsigned short* __restrict__ ablo,
    float* __restrict__ out)
{
    __shared__ float Rsh[kJ][9];
    __shared__ float Jr[kJ][3];
    __shared__ float G[kJ][12];
    __shared__ float Ash[kJ][12];

    int b = blockIdx.x;
    int t = threadIdx.x;
    int mtile = b >> 4, minr = b & 15;

    if (t < kJ) {
        float rx, ry, rz;
        if (t == 0) {
            rx = gor[b * 3 + 0]; ry = gor[b * 3 + 1]; rz = gor[b * 3 + 2];
        } else {
            int o = b * 69 + (t - 1) * 3;
            rx = pose[o]; ry = pose[o + 1]; rz = pose[o + 2];
        }
        float ex = rx + 1e-8f, ey = ry + 1e-8f, ez = rz + 1e-8f;
        float ang = sqrtf(ex * ex + ey * ey + ez * ez);
        float x = rx / ang, y = ry / ang, z = rz / ang;
        float s = sinf(ang), c = cosf(ang), oc = 1.0f - c;
        float r[9];
        r[0] = 1.0f - oc * (y * y + z * z);
        r[1] = -s * z + oc * (x * y);
        r[2] =  s * y + oc * (x * z);
        r[3] =  s * z + oc * (x * y);
        r[4] = 1.0f - oc * (x * x + z * z);
        r[5] = -s * x + oc * (y * z);
        r[6] = -s * y + oc * (x * z);
        r[7] =  s * x + oc * (y * z);
        r[8] = 1.0f - oc * (x * x + y * y);
        #pragma unroll
        for (int i = 0; i < 9; i++) Rsh[t][i] = r[i];
        float* ro = out + O_ROT + (size_t)b * (kJ * 9) + (size_t)t * 9;
        #pragma unroll
        for (int i = 0; i < 9; i++) ro[i] = r[i];
        if (t >= 1) {
            #pragma unroll
            for (int i = 0; i < 9; i++) {
                int k = (t - 1) * 9 + i;
                float val = r[i] - ((i == 0 || i == 4 || i == 8) ? 1.0f : 0.0f);
                aswz[a_idx(mtile, minr, k)] = f2bf(val);
            }
        }
        // Jr = (reduced js partials) dot [betas | 1]
        float bt[kNB];
        #pragma unroll
        for (int l = 0; l < kNB; l++) bt[l] = betas[b * kNB + l];
        #pragma unroll
        for (int k2 = 0; k2 < 3; k2++) {
            float row[11];
            #pragma unroll
            for (int i = 0; i < 11; i++) row[i] = 0.f;
            #pragma unroll
            for (int c8 = 0; c8 < 8; c8++) {
                const float* pp = jsp + ((size_t)t * 8 + c8) * 33 + k2 * 11;
                #pragma unroll
                for (int i = 0; i < 11; i++) row[i] += pp[i];
            }
            float acc = row[10];
            #pragma unroll
            for (int l = 0; l < kNB; l++) acc += bt[l] * row[l];
            Jr[t][k2] = acc;
        }
    } else if (t < 41 + kJ) {
        int idx = t - kJ;
        if (idx < 17) {
            int k = kP + idx;
            float val = 0.f;
            if (idx < kNB)          val = betas[b * kNB + idx];
            else if (k == kP + kNB) val = 1.0f;
            aswz[a_idx(mtile, minr, k)] = f2bf(val);
        }
    }
    __syncthreads();

    if (t == 0) {
        const int par[kJ] = {-1,0,0,0,1,2,3,4,5,6,7,8,9,9,9,12,13,14,16,17,18,19,20,21};
        #pragma unroll
        for (int m = 0; m < 3; m++) {
            #pragma unroll
            for (int n = 0; n < 3; n++) G[0][m * 4 + n] = Rsh[0][m * 3 + n];
            G[0][m * 4 + 3] = Jr[0][m];
        }
        for (int i = 1; i < kJ; i++) {
            int p = par[i];
            float rel[3];
            #pragma unroll
            for (int k = 0; k < 3; k++) rel[k] = Jr[i][k] - Jr[p][k];
            #pragma unroll
            for (int m = 0; m < 3; m++) {
                float g0 = G[p][m * 4 + 0], g1 = G[p][m * 4 + 1], g2 = G[p][m * 4 + 2];
                #pragma unroll
                for (int n = 0; n < 3; n++) {
                    G[i][m * 4 + n] = g0 * Rsh[i][0 * 3 + n]
                                    + g1 * Rsh[i][1 * 3 + n]
                                    + g2 * Rsh[i][2 * 3 + n];
                }
                G[i][m * 4 + 3] = g0 * rel[0] + g1 * rel[1] + g2 * rel[2]
                                + G[p][m * 4 + 3];
            }
        }
    }
    __syncthreads();

    if (t < kJ) {
        float* jo = out + O_JOINTS + (size_t)b * (kJ * 3) + (size_t)t * 3;
        #pragma unroll
        for (int m = 0; m < 3; m++) {
            float g0 = G[t][m * 4 + 0], g1 = G[t][m * 4 + 1], g2 = G[t][m * 4 + 2];
            float tr = G[t][m * 4 + 3]
                     - (g0 * Jr[t][0] + g1 * Jr[t][1] + g2 * Jr[t][2]);
            Ash[t][m * 4 + 0] = g0;
            Ash[t][m * 4 + 1] = g1;
            Ash[t][m * 4 + 2] = g2;
            Ash[t][m * 4 + 3] = tr;
            jo[m] = G[t][m * 4 + 3] - G[0][m * 4 + 3];
        }
        if (t == 0) {
            #pragma unroll
            for (int k = 0; k < 3; k++) wsRoot[b * 3 + k] = G[0][k * 4 + 3];
        }
    }
    __syncthreads();

    // bf16 hi/lo B-operand fragment for k_lbs MFMA
    {
        short8 h8, l8;
        #pragma unroll
        for (int e = 0; e < 8; e++) {
            int j = (t >> 4) * 8 + e;
            int m = t & 15;
            float val = (j < kJ && m < 12) ? Ash[j][m] : 0.f;
            unsigned short h = f2bf(val);
            h8[e] = (short)h;
            l8[e] = (short)f2bf(val - bf2f(h));
        }
        *(short8*)(abhi + (size_t)b * 512 + t * 8) = h8;
        *(short8*)(ablo + (size_t)b * 512 + t * 8) = l8;
    }
}

// ---------------------------------------------------------------------------
// k_gemm: v_posed[b][n] = A(1024x224) @ B(224x20670) -> out[O_VERTS] (fp32).
// ---------------------------------------------------------------------------
__global__ __launch_bounds__(256) void k_gemm(
    const unsigned short* __restrict__ A,
    const unsigned short* __restrict__ B,
    float* __restrict__ out)
{
    int tid = threadIdx.x;
    int lane = tid & 63;
    int wid = tid >> 6;
    int m0t = blockIdx.y * 8 + (wid >> 1) * 4;
    int n0t = blockIdx.x * 8 + (wid & 1) * 4;

    float4v acc[4][4];
    #pragma unroll
    for (int i = 0; i < 4; i++)
        #pragma unroll
        for (int j = 0; j < 4; j++)
            acc[i][j] = (float4v){0.f, 0.f, 0.f, 0.f};

    #pragma unroll
    for (int kt = 0; kt < 7; kt++) {
        short8 a[4], b[4];
        #pragma unroll
        for (int i = 0; i < 4; i++)
            a[i] = *(const short8*)(A + ((size_t)(m0t + i) * 7 + kt) * 512 + lane * 8);
        #pragma unroll
        for (int j = 0; j < 4; j++)
            b[j] = *(const short8*)(B + ((size_t)(n0t + j) * 7 + kt) * 512 + lane * 8);
        #pragma unroll
        for (int i = 0; i < 4; i++)
            #pragma unroll
            for (int j = 0; j < 4; j++)
                acc[i][j] = __builtin_amdgcn_mfma_f32_16x16x32_bf16(
                    a[i], b[j], acc[i][j], 0, 0, 0);
    }

    int rbase = (lane >> 4) * 4;
    int col = lane & 15;
    #pragma unroll
    for (int i = 0; i < 4; i++) {
        #pragma unroll
        for (int j = 0; j < 4; j++) {
            int n = (n0t + j) * 16 + col;
            if (n < kN) {
                #pragma unroll
                for (int reg = 0; reg < 4; reg++) {
                    int brow = (m0t + i) * 16 + rbase + reg;
                    out[O_VERTS + (size_t)brow * kN + n] = acc[i][j][reg];
                }
            }
        }
    }
}

// ---------------------------------------------------------------------------
// k_lbs (MFMA): Tv(256v x 12) = W_tile @ A_flat on matrix cores, hi/lo bf16
// split (3 MFMAs; dropped Wlo@Alo <= 2^-18 rel).  W fragments built
// IN-REGISTER from global W (two aligned float4 loads per tile; chunk 3 =
// K-pad zeros) -- no W staging buffers, no overlap risk.
// Block: 256 thr / 4 waves; wave w owns v-tiles w*4..w*4+3; per batch:
// 12 MFMA -> LDS (stride-13 pad) -> per-thread apply.  Grid 27 x 128.
// ---------------------------------------------------------------------------
__global__ __launch_bounds__(256) void k_lbs(
    const float* __restrict__ amb0,
    const float* __restrict__ amb1,
    const unsigned short* __restrict__ abhi,
    const unsigned short* __restrict__ ablo,
    const float* __restrict__ wsRoot,
    float* __restrict__ out)
{
    const float* W = amb0_is_weights(amb0) ? amb0 : amb1;
    __shared__ float ldsT[256 * 13];

    int t = threadIdx.x;
    int lane = t & 63, w = t >> 6;
    int vb = blockIdx.x;            // 0..26
    int b0 = blockIdx.y * kLbsTB;
    int chunk = lane >> 4;          // k-slice 0..3 (3 = pad)

    short8 wh[4], wl[4];
    #pragma unroll
    for (int i = 0; i < 4; i++) {
        int row = vb * 256 + (w * 4 + i) * 16 + (lane & 15);
        float vals[8];
        if (chunk < 3 && row < kV) {
            const float4v* p = (const float4v*)(W + (size_t)row * kJ + chunk * 8);
            float4v x0 = p[0], x1 = p[1];
            vals[0] = x0[0]; vals[1] = x0[1]; vals[2] = x0[2]; vals[3] = x0[3];
            vals[4] = x1[0]; vals[5] = x1[1]; vals[6] = x1[2]; vals[7] = x1[3];
        } else {
            #pragma unroll
            for (int e = 0; e < 8; e++) vals[e] = 0.f;
        }
        #pragma unroll
        for (int e = 0; e < 8; e++) {
            unsigned short h = f2bf(vals[e]);
            wh[i][e] = (short)h;
            wl[i][e] = (short)f2bf(vals[e] - bf2f(h));
        }
    }

    int v = vb * 256 + t;
    bool act = (v < kV);
    int crow = (lane >> 4) * 4;
    int ccol = lane & 15;

    #pragma unroll 1
    for (int tb = 0; tb < kLbsTB; tb++) {
        int b = b0 + tb;
        short8 ah = *(const short8*)(abhi + (size_t)b * 512 + lane * 8);
        short8 al = *(const short8*)(ablo + (size_t)b * 512 + lane * 8);

        #pragma unroll
        for (int i = 0; i < 4; i++) {
            float4v acc = (float4v){0.f, 0.f, 0.f, 0.f};
            acc = __builtin_amdgcn_mfma_f32_16x16x32_bf16(wl[i], ah, acc, 0, 0, 0);
            acc = __builtin_amdgcn_mfma_f32_16x16x32_bf16(wh[i], al, acc, 0, 0, 0);
            acc = __builtin_amdgcn_mfma_f32_16x16x32_bf16(wh[i], ah, acc, 0, 0, 0);
            if (ccol < 12) {
                int base = (w * 4 + i) * 16 * 13;
                #pragma unroll
                for (int reg = 0; reg < 4; reg++)
                    ldsT[base + (crow + reg) * 13 + ccol] = acc[reg];
            }
        }
        __syncthreads();

        {
            const float* T = &ldsT[t * 13];
            float r0 = wsRoot[(size_t)b * 3 + 0];
            float r1 = wsRoot[(size_t)b * 3 + 1];
            float r2 = wsRoot[(size_t)b * 3 + 2];
            if (act) {
                float* op = out + O_VERTS + ((size_t)b * kV + v) * 3;
                float x = op[0], y = op[1], z = op[2];
                float o0 = T[0] * x + T[1] * y + T[2]  * z + T[3]  - r0;
                float o1 = T[4] * x + T[5] * y + T[6]  * z + T[7]  - r1;
                float o2 = T[8] * x + T[9] * y + T[10] * z + T[11] - r2;
                op[0] = o0; op[1] = o1; op[2] = o2;
            }
        }
        __syncthreads();
    }
}

// ---------------------------------------------------------------------------
// k_jfv: jfv[b0..b0+3] = Jh @ verts, root17 subtraction folded in.
// 256 blocks x 1024 threads; one Jh row per wave (wave 0 adds row 16).
// ---------------------------------------------------------------------------
__global__ __launch_bounds__(1024) void k_jfv(
    const float* __restrict__ Jh,
    const float* __restrict__ verts,
    float* __restrict__ out)
{
    int b0 = blockIdx.x * kJB;
    int t = threadIdx.x;
    int wave = t >> 6, lane = t & 63;
    int j0 = wave;
    bool has2 = (wave == 0);

    float acc0[kJB][3], acc1[kJB][3];
    #pragma unroll
    for (int bb = 0; bb < kJB; bb++)
        #pragma unroll
        for (int k = 0; k < 3; k++) { acc0[bb][k] = 0.f; acc1[bb][k] = 0.f; }

    const float* Jr0 = Jh + (size_t)j0 * kV;
    const float* Jr1 = Jh + (size_t)16 * kV;

    for (int v = lane; v < kV; v += 64) {
        float w0 = Jr0[v];
        float w1 = has2 ? Jr1[v] : 0.f;
        #pragma unroll
        for (int bb = 0; bb < kJB; bb++) {
            const float* vp = verts + ((size_t)(b0 + bb) * kV + v) * 3;
            float vx = vp[0], vy = vp[1], vz = vp[2];
            acc0[bb][0] += w0 * vx; acc0[bb][1] += w0 * vy; acc0[bb][2] += w0 * vz;
            acc1[bb][0] += w1 * vx; acc1[bb][1] += w1 * vy; acc1[bb][2] += w1 * vz;
        }
    }
    #pragma unroll
    for (int off = 32; off > 0; off >>= 1) {
        #pragma unroll
        for (int bb = 0; bb < kJB; bb++)
            #pragma unroll
            for (int k = 0; k < 3; k++) {
                acc0[bb][k] += __shfl_down(acc0[bb][k], off, 64);
                acc1[bb][k] += __shfl_down(acc1[bb][k], off, 64);
            }
    }
    __shared__ float fin[kJB][52];
    if (lane == 0) {
        #pragma unroll
        for (int bb = 0; bb < kJB; bb++)
            #pragma unroll
            for (int k = 0; k < 3; k++) {
                fin[bb][j0 * 3 + k] = acc0[bb][k];
                if (has2) fin[bb][48 + k] = acc1[bb][k];
            }
    }
    __syncthreads();
    if (t < kJB * 51) {
        int bb = t / 51, i = t - bb * 51;
        out[O_JFV + (size_t)(b0 + bb) * 51 + i] = fin[bb][i] - fin[bb][i % 3];
    }
}

extern "C" void kernel_launch(void* const* d_in, const int* in_sizes, int n_in,
                              void* d_out, int out_size, void* d_ws, size_t ws_size,
                              hipStream_t stream) {
    const float *pose = nullptr, *betas = nullptr, *gor = nullptr, *vt = nullptr,
                *sd = nullptr, *pd = nullptr, *Jh = nullptr;
    const float *amb0 = nullptr, *amb1 = nullptr;
    for (int i = 0; i < n_in; i++) {
        const float* p = (const float*)d_in[i];
        switch (in_sizes[i]) {
            case 70656:   pose  = p; break;
            case 10240:   betas = p; break;
            case 3072:    gor   = p; break;
            case 20670:   vt    = p; break;
            case 206700:  sd    = p; break;
            case 4278690: pd    = p; break;
            case 117130:  Jh    = p; break;
            case 165360:  if (!amb0) amb0 = p; else amb1 = p; break;
            default: break;
        }
    }

    float* ws = (float*)d_ws;
    float* jsp     = ws + WS_JSP;
    float* wsRoot  = ws + WS_ROOT;
    unsigned short* abhi = (unsigned short*)(ws + WS_ABHI);
    unsigned short* ablo = (unsigned short*)(ws + WS_ABLO);
    unsigned short* aswz = (unsigned short*)(ws + WS_ASWZ);
    unsigned short* bswz = (unsigned short*)(ws + WS_BSWZ);

    float* out = (float*)d_out;

    k_sfb  <<<dim3(kJsBlocks + kPbBlocks), dim3(256), 0, stream>>>(
        amb0, amb1, sd, vt, pd, jsp, bswz);
    k_pose <<<dim3(kB),                 dim3(64),  0, stream>>>(
        pose, betas, gor, jsp, wsRoot, aswz, abhi, ablo, out);
    k_gemm <<<dim3(kNT / 8, kB / 128),  dim3(256), 0, stream>>>(aswz, bswz, out);
    k_lbs  <<<dim3(27, kB / kLbsTB),    dim3(256), 0, stream>>>(
        amb0, amb1, abhi, ablo, wsRoot, out);
    k_jfv  <<<dim3(kB / kJB),           dim3(1024), 0, stream>>>(
        Jh, out + O_VERTS, out);
}